// Round 5
// baseline (7912.565 us; speedup 1.0000x reference)
//
#include <hip/hip_runtime.h>
#include <math.h>

namespace {
constexpr int kH    = 256;   // hidden
constexpr int kM    = 32;    // stack value dim
constexpr int kIn   = 131;   // input dim
constexpr int kOut  = 131;   // output dim
constexpr int kB    = 32;    // batch
constexpr int kTenc = 128;   // encoder steps
constexpr int kT    = 256;   // total sequential steps
constexpr int kCap  = 257;   // stack capacity
constexpr int kG    = 1024;  // 4*H gates
constexpr int kK    = 288;   // H + M combined recurrent input
constexpr int kSp   = 3;     // K-splits (cooperating blocks per batch)
constexpr int kKs   = 96;    // K per split
constexpr int kWR   = 192;   // fp32 weights per thread (2 gates x 96 k), VGPR-resident
constexpr int kVs   = 36;    // Vbuf row stride (bank = (4i+m)%32 -> <=2-way)
}

__device__ __forceinline__ float frcp(float x){ return __builtin_amdgcn_rcpf(x); }
__device__ __forceinline__ float sigf(float x){ return frcp(1.0f + __expf(-x)); }
__device__ __forceinline__ float tanhf_fast(float x){
  return 1.0f - 2.0f*frcp(__expf(2.0f*x) + 1.0f);   // saturates via inf/0
}

template<int PAT>
__device__ __forceinline__ float swz(float x){
  return __int_as_float(__builtin_amdgcn_ds_swizzle(__float_as_int(x), PAT));
}

// dst[c*R + r] = src[r*stride + col0 + c]
__global__ void k_transpose(float* __restrict__ dst, const float* __restrict__ src,
                            int R, int C, int stride, int col0){
  int idx = blockIdx.x*256 + threadIdx.x;
  if (idx >= R*C) return;
  int rr = idx / C;
  int cc = idx - rr*C;
  dst[cc*R + rr] = src[rr*stride + col0 + cc];
}

// fp32 weight pack for the K-split resident k_seq.
// dst[(s*kWR + i)*512 + tid], i = gs*kKs + kk:
//   thread tid (j=tid&255, gp=tid>>8) gate col=(2gp+gs)*256+j, k = s*kKs+kk
//   k<256 -> Whh[col][k], else Wih[col][131 + (k-256)]
__global__ void k_packw(float* __restrict__ dst, const float* __restrict__ Wih,
                        const float* __restrict__ Whh){
  int idx = blockIdx.x*256 + threadIdx.x;
  if (idx >= kSp*kWR*512) return;
  int tid  = idx & 511;
  int rest = idx >> 9;             // s*kWR + i
  int s  = rest / kWR, i = rest - s*kWR;
  int gs = i / kKs,   kk = i - gs*kKs;
  int j  = tid & 255, gp = tid >> 8;
  int col = (2*gp + gs)*256 + j;
  int k   = s*kKs + kk;
  dst[idx] = (k < kH) ? Whh[col*kH + k] : Wih[col*(kIn+kM) + kIn + (k - kH)];
}

// gatesXp[t][b][j][g] = sum_k x_t[b][k]*Wih[g*256+j][k] + bih + bhh
__global__ void k_gatesx(const float* __restrict__ X, const float* __restrict__ Y,
                         const float* __restrict__ WixT_e, const float* __restrict__ WixT_d,
                         const float* __restrict__ bih_e, const float* __restrict__ bhh_e,
                         const float* __restrict__ bih_d, const float* __restrict__ bhh_d,
                         float* __restrict__ gatesXp){
  const int t   = blockIdx.x;
  const int col = blockIdx.y*256 + threadIdx.x;
  __shared__ float xl[kB*kIn];
  const float* xsrc;
  if (t < kTenc)       xsrc = X + (size_t)t*kB*kIn;
  else if (t == kTenc) xsrc = X + (size_t)kTenc*kB*kIn;
  else                 xsrc = Y + (size_t)(t-kTenc-1)*kB*kIn;
  for (int i = threadIdx.x; i < kB*kIn; i += 256) xl[i] = xsrc[i];
  __syncthreads();
  const float* WT   = (t < kTenc) ? WixT_e : WixT_d;
  const float  bias = (t < kTenc) ? (bih_e[col] + bhh_e[col]) : (bih_d[col] + bhh_d[col]);
  float acc[kB];
#pragma unroll
  for (int b = 0; b < kB; ++b) acc[b] = bias;
  for (int k = 0; k < kIn; ++k){
    float wk = WT[k*kG + col];
#pragma unroll
    for (int b = 0; b < kB; ++b) acc[b] += wk * xl[b*kIn + k];
  }
  const int j = col & 255, g = col >> 8;
#pragma unroll
  for (int b = 0; b < kB; ++b)
    gatesXp[(((size_t)t*kB + b)*256 + j)*4 + g] = acc[b];
}

__device__ __forceinline__ float wave_suffix_incl(float x, int lane){
#pragma unroll
  for (int off = 1; off < 64; off <<= 1){
    float t = __shfl_down(x, off);
    if (lane + off < 64) x += t;
  }
  return x;
}

__global__ void __launch_bounds__(512, 2)
k_seq(const float* __restrict__ gatesXp, const float* __restrict__ wblob,
      float* __restrict__ pbuf, unsigned int* flags,
      const float* __restrict__ Wd, const float* __restrict__ bd,
      const float* __restrict__ Wu, const float* __restrict__ bu,
      const float* __restrict__ Wv, const float* __restrict__ bv,
      const float* __restrict__ h0, const float* __restrict__ c0,
      float* __restrict__ Hdec){
  const int bid  = blockIdx.x;
  const int b    = bid / kSp;      // batch element
  const int sp   = bid - b*kSp;    // K-split id 0..2
  const int tid  = threadIdx.x;
  const int lane = tid & 63;
  const int wave = tid >> 6;
  const int j    = tid & 255;
  const int gp   = tid >> 8;       // 0: gates i,f ; 1: gates g,o
  const int col0 = (2*gp)*256 + j;
  const int col1 = col0 + 256;

  __shared__ __align__(16) float z[kK];   // [h(256) | r(32)]
  __shared__ float cst[kH];
  __shared__ float gbuf[2][256];          // full g,o gates exchange
  __shared__ float sbuf[kCap];
  __shared__ float coeff[kCap];
  __shared__ float Vbuf[kCap*kVs];

  if (tid < kH){ z[tid] = h0[tid]; cst[tid] = c0[tid]; }
  if (tid >= kH && tid < kK) z[tid] = 0.f;
  for (int i = tid; i < kCap; i += 512) sbuf[i] = 0.f;
  if (tid < kVs) Vbuf[tid] = 0.f;         // row 0 (never written, coeff=0)
  __syncthreads();

  float wreg[kWR];

  for (int seg = 0; seg < 2; ++seg){
    // load my fp32 weight slice into VGPRs (once per segment)
    {
      const float* wb = wblob + ((size_t)(seg*kSp + sp)*kWR)*512 + tid;
#pragma unroll
      for (int i = 0; i < kWR; ++i) wreg[i] = wb[(size_t)i*512];
    }

    for (int tt = 0; tt < 128; ++tt){
      const int t = seg*128 + tt;

      // x-part gates (i,f,g,o) of unit j — all threads
      float4 gx = *(const float4*)(gatesXp + (((size_t)t*kB + b)*256 + j)*4);

      // ---- phase 1: matvec over my K-range, 2 gates, pure VGPR
      float a00=0.f,a01=0.f,a02=0.f,a03=0.f,a10=0.f,a11=0.f,a12=0.f,a13=0.f;
      {
        const float4* z4 = (const float4*)z + sp*(kKs/4);
#pragma unroll
        for (int c = 0; c < kKs/4; ++c){
          float4 zz = z4[c];
          a00 += wreg[4*c+0]*zz.x; a01 += wreg[4*c+1]*zz.y;
          a02 += wreg[4*c+2]*zz.z; a03 += wreg[4*c+3]*zz.w;
          a10 += wreg[kKs+4*c+0]*zz.x; a11 += wreg[kKs+4*c+1]*zz.y;
          a12 += wreg[kKs+4*c+2]*zz.z; a13 += wreg[kKs+4*c+3]*zz.w;
        }
      }
      const float acc0 = (a00+a01)+(a02+a03);
      const float acc1 = (a10+a11)+(a12+a13);

      // ---- publish partials (agent-scope), release flag
      const int par = t & 1;
      const unsigned want = (unsigned)(t + 1);
      {
        float* myp = pbuf + (((size_t)par*kSp + sp)*kB + b)*kG;
        __hip_atomic_store(&myp[col0], acc0, __ATOMIC_RELAXED, __HIP_MEMORY_SCOPE_AGENT);
        __hip_atomic_store(&myp[col1], acc1, __ATOMIC_RELAXED, __HIP_MEMORY_SCOPE_AGENT);
      }
      __threadfence();
      __syncthreads();
      if (tid == 0)
        __hip_atomic_store(&flags[(par*kSp + sp)*kB + b], want,
                           __ATOMIC_RELEASE, __HIP_MEMORY_SCOPE_AGENT);

      // ---- gather partner partials; sum in uniform order s2=0,1,2 (deterministic
      //      across siblings -> identical h/c/stack everywhere, no divergence)
      float g0 = gp ? gx.z : gx.x;
      float g1 = gp ? gx.w : gx.y;
#pragma unroll
      for (int s2 = 0; s2 < kSp; ++s2){
        if (s2 == sp){ g0 += acc0; g1 += acc1; }
        else {
          unsigned int* fl = &flags[(par*kSp + s2)*kB + b];
          while (__hip_atomic_load(fl, __ATOMIC_ACQUIRE, __HIP_MEMORY_SCOPE_AGENT) < want){}
          float* pp = pbuf + (((size_t)par*kSp + s2)*kB + b)*kG;
          g0 += __hip_atomic_load(&pp[col0], __ATOMIC_RELAXED, __HIP_MEMORY_SCOPE_AGENT);
          g1 += __hip_atomic_load(&pp[col1], __ATOMIC_RELAXED, __HIP_MEMORY_SCOPE_AGENT);
        }
      }
      if (gp){ gbuf[0][j] = g0; gbuf[1][j] = g1; }
      __syncthreads();                       // A: full gates ready

      // ---- phase 2: LSTM cell (threads 0..255)
      if (tid < kH){
        float ig = sigf(g0);                 // gate i
        float fg = sigf(g1);                 // gate f
        float g2 = tanhf_fast(gbuf[0][j]);   // gate g
        float og = sigf(gbuf[1][j]);         // gate o
        float cn = fg*cst[j] + ig*g2;
        cst[j] = cn;
        float hn = og*tanhf_fast(cn);
        z[j] = hn;
        if (seg && sp == 0)
          Hdec[(((size_t)(t - kTenc))*kB + b)*kH + j] = hn;
      }
      __syncthreads();                       // B: h ready

      // ---- phase 3+4: controller + stack (wave0: d,u + scan; tid>=256: v)
      const int cnt = t + 1;
      if (wave == 0){
        const float* Wdu = (lane < 32) ? Wd : Wu;
        const int kl = lane & 31;
        float p = 0.f;
#pragma unroll
        for (int q2 = 0; q2 < 8; ++q2) p += z[kl + 32*q2] * Wdu[kl + 32*q2];
        p += swz<0x401F>(p); p += swz<0x201F>(p); p += swz<0x101F>(p);
        p += swz<0x081F>(p); p += swz<0x041F>(p);
        float o  = __shfl_xor(p, 32);
        float dd = sigf(((lane < 32) ? p : o) + bd[0]);
        float uu = sigf(((lane < 32) ? o : p) + bu[0]);

        float sm[5], sn[5];
        float csum = 0.f;
#pragma unroll
        for (int qq = 0; qq < 5; ++qq){
          int i = lane*5 + qq;
          float sv = (i < cnt) ? sbuf[i] : 0.f;
          sm[qq] = sv; csum += sv;
        }
        float run = wave_suffix_incl(csum, lane) - csum;
        float csum2 = 0.f;
#pragma unroll
        for (int qq = 4; qq >= 0; --qq){
          int i = lane*5 + qq;
          float sv;
          if (i == cnt)      sv = dd;
          else if (i < cnt)  sv = fmaxf(sm[qq] - fmaxf(uu - run, 0.f), 0.f);
          else               sv = 0.f;
          sn[qq] = sv;
          run  += sm[qq];
          csum2 += sv;
        }
#pragma unroll
        for (int qq = 0; qq < 5; ++qq){
          int i = lane*5 + qq;
          if (i < kCap) sbuf[i] = sn[qq];
        }
        float run2 = wave_suffix_incl(csum2, lane) - csum2;
#pragma unroll
        for (int qq = 4; qq >= 0; --qq){
          int i = lane*5 + qq;
          float cf = fminf(sn[qq], fmaxf(1.f - run2, 0.f));
          if (i < kCap) coeff[i] = cf;
          run2 += sn[qq];
        }
      } else if (tid >= 256){
        const int m = (tid - 256) >> 3, l = tid & 7;
        float p = 0.f;
        for (int k2 = l; k2 < kH; k2 += 8) p += z[k2] * Wv[m*kH + k2];
        p += swz<0x101F>(p); p += swz<0x081F>(p); p += swz<0x041F>(p);
        if (l == 0) Vbuf[cnt*kVs + m] = tanhf_fast(p + bv[m]);
      }
      __syncthreads();                       // D: coeff + Vbuf[cnt] ready

      // ---- phase 5: r[m] = sum_i coeff[i]*Vbuf[i][m]
      if (tid < kH){
        const int m = tid >> 3, l = tid & 7;
        float p = 0.f;
        for (int i = l; i <= cnt; i += 8) p += coeff[i]*Vbuf[i*kVs + m];
        p += swz<0x101F>(p); p += swz<0x081F>(p); p += swz<0x041F>(p);
        if (l == 0) z[kH + m] = p;
      }
      __syncthreads();                       // E: z ready for next step
    }
  }
}

// oc = tanh(h@Wo^T + bo); out = log_softmax(oc@Wlin^T + blin)
__global__ void k_out(const float* __restrict__ Hdec,
                      const float* __restrict__ WoT, const float* __restrict__ bo,
                      const float* __restrict__ WlinT, const float* __restrict__ blin,
                      float* __restrict__ out){
  const int row = blockIdx.x;
  const int tid = threadIdx.x;
  __shared__ float hr[kH], oc[kH], lg[kOut], st[2];
  hr[tid] = Hdec[(size_t)row*kH + tid];
  __syncthreads();
  float a = bo[tid];
  for (int k = 0; k < kH; ++k) a += hr[k]*WoT[k*kH + tid];
  oc[tid] = tanhf(a);
  __syncthreads();
  if (tid < kOut){
    float a2 = blin[tid];
    for (int k = 0; k < kH; ++k) a2 += oc[k]*WlinT[k*kOut + tid];
    lg[tid] = a2;
  }
  __syncthreads();
  if (tid < 64){
    float mx = -3.4e38f;
    for (int i = tid; i < kOut; i += 64) mx = fmaxf(mx, lg[i]);
#pragma unroll
    for (int off = 32; off; off >>= 1) mx = fmaxf(mx, __shfl_down(mx, off));
    mx = __shfl(mx, 0);
    float se = 0.f;
    for (int i = tid; i < kOut; i += 64) se += expf(lg[i] - mx);
#pragma unroll
    for (int off = 32; off; off >>= 1) se += __shfl_down(se, off);
    if (tid == 0){ st[0] = mx; st[1] = logf(se); }
  }
  __syncthreads();
  if (tid < kOut) out[(size_t)row*kOut + tid] = lg[tid] - st[0] - st[1];
}

extern "C" void kernel_launch(void* const* d_in, const int* in_sizes, int n_in,
                              void* d_out, int out_size, void* d_ws, size_t ws_size,
                              hipStream_t stream){
  (void)in_sizes; (void)n_in; (void)out_size; (void)ws_size;
  const float* X     = (const float*)d_in[0];
  const float* Y     = (const float*)d_in[1];
  const float* Wih_e = (const float*)d_in[2];
  const float* Whh_e = (const float*)d_in[3];
  const float* bih_e = (const float*)d_in[4];
  const float* bhh_e = (const float*)d_in[5];
  const float* Wih_d = (const float*)d_in[6];
  const float* Whh_d = (const float*)d_in[7];
  const float* bih_d = (const float*)d_in[8];
  const float* bhh_d = (const float*)d_in[9];
  const float* Wd    = (const float*)d_in[10];
  const float* bd    = (const float*)d_in[11];
  const float* Wu    = (const float*)d_in[12];
  const float* bu    = (const float*)d_in[13];
  const float* Wv    = (const float*)d_in[14];
  const float* bv    = (const float*)d_in[15];
  const float* Wo    = (const float*)d_in[16];
  const float* bo    = (const float*)d_in[17];
  const float* Wlin  = (const float*)d_in[18];
  const float* blin  = (const float*)d_in[19];
  const float* h0    = (const float*)d_in[20];
  const float* c0    = (const float*)d_in[21];
  float* out = (float*)d_out;

  float* ws = (float*)d_ws;
  size_t o = 0;
  float* gatesXp = ws + o; o += (size_t)kT*kB*kG;        // 8,388,608
  float* WixT_e  = ws + o; o += (size_t)kIn*kG;
  float* WixT_d  = ws + o; o += (size_t)kIn*kG;
  float* WoT     = ws + o; o += (size_t)kH*kH;
  float* WlinT   = ws + o; o += (size_t)kH*kOut;
  float* Hdec    = ws + o; o += (size_t)128*kB*kH;       // 1,048,576
  float* wblob   = ws + o; o += (size_t)2*kSp*kWR*512;   // 589,824
  float* pbuf    = ws + o; o += (size_t)2*kSp*kB*kG;     // 196,608
  unsigned int* flags = (unsigned int*)(ws + o); o += 64; // 2*3*32 = 192 uints

  // flags must be zero at每 launch (ws re-poisoned to 0xAA by harness)
  hipMemsetAsync(flags, 0, 2*kSp*kB*sizeof(unsigned int), stream);

  auto tr = [&](float* dst, const float* src, int R, int C, int stride, int col0){
    int n = R*C;
    k_transpose<<<(n+255)/256, 256, 0, stream>>>(dst, src, R, C, stride, col0);
  };
  tr(WixT_e, Wih_e, kG, kIn, kIn+kM, 0);
  tr(WixT_d, Wih_d, kG, kIn, kIn+kM, 0);
  tr(WoT,   Wo,   kH,  kH, kH, 0);
  tr(WlinT, Wlin, kOut, kH, kH, 0);

  const int npack = kSp*kWR*512;
  k_packw<<<(npack+255)/256, 256, 0, stream>>>(wblob,                      Wih_e, Whh_e);
  k_packw<<<(npack+255)/256, 256, 0, stream>>>(wblob + (size_t)npack,      Wih_d, Whh_d);

  k_gatesx<<<dim3(kT,4), 256, 0, stream>>>(X, Y, WixT_e, WixT_d,
                                           bih_e, bhh_e, bih_d, bhh_d, gatesXp);
  k_seq<<<kB*kSp, 512, 0, stream>>>(gatesXp, wblob, pbuf, flags,
                                    Wd, bd, Wu, bu, Wv, bv, h0, c0, Hdec);
  k_out<<<128*kB, 256, 0, stream>>>(Hdec, WoT, bo, WlinT, blin, out);
}

// Round 6
// 2453.770 us; speedup vs baseline: 3.2247x; 3.2247x over previous
//
#include <hip/hip_runtime.h>
#include <math.h>

namespace {
constexpr int kH    = 256;   // hidden
constexpr int kM    = 32;    // stack value dim
constexpr int kIn   = 131;   // input dim
constexpr int kOut  = 131;   // output dim
constexpr int kB    = 32;    // batch
constexpr int kTenc = 128;   // encoder steps
constexpr int kT    = 256;   // total sequential steps
constexpr int kCap  = 257;   // stack capacity
constexpr int kG    = 1024;  // 4*H gates
constexpr int kK    = 288;   // H + M combined recurrent input
constexpr int kSp   = 4;     // K-splits (cooperating blocks per batch)
constexpr int kKs   = 72;    // K per split
constexpr int kWR   = 144;   // fp32 weights per thread (2 gates x 72 k), VGPR-resident
constexpr int kVs   = 36;    // Vbuf row stride (bank = (4i+m)%32 -> <=2-way)
}

__device__ __forceinline__ float frcp(float x){ return __builtin_amdgcn_rcpf(x); }
__device__ __forceinline__ float sigf(float x){ return frcp(1.0f + __expf(-x)); }
__device__ __forceinline__ float tanhf_fast(float x){
  return 1.0f - 2.0f*frcp(__expf(2.0f*x) + 1.0f);   // saturates via inf/0
}

template<int PAT>
__device__ __forceinline__ float swz(float x){
  return __int_as_float(__builtin_amdgcn_ds_swizzle(__float_as_int(x), PAT));
}

// dst[c*R + r] = src[r*stride + col0 + c]
__global__ void k_transpose(float* __restrict__ dst, const float* __restrict__ src,
                            int R, int C, int stride, int col0){
  int idx = blockIdx.x*256 + threadIdx.x;
  if (idx >= R*C) return;
  int rr = idx / C;
  int cc = idx - rr*C;
  dst[cc*R + rr] = src[rr*stride + col0 + cc];
}

// fp32 weight pack for the K-split resident k_seq.
// dst[(s*kWR + i)*512 + tid], i = gs*kKs + kk:
//   thread tid (j=tid&255, gp=tid>>8) gate col=(2gp+gs)*256+j, k = s*kKs+kk
//   k<256 -> Whh[col][k], else Wih[col][131 + (k-256)]
__global__ void k_packw(float* __restrict__ dst, const float* __restrict__ Wih,
                        const float* __restrict__ Whh){
  int idx = blockIdx.x*256 + threadIdx.x;
  if (idx >= kSp*kWR*512) return;
  int tid  = idx & 511;
  int rest = idx >> 9;             // s*kWR + i
  int s  = rest / kWR, i = rest - s*kWR;
  int gs = i / kKs,   kk = i - gs*kKs;
  int j  = tid & 255, gp = tid >> 8;
  int col = (2*gp + gs)*256 + j;
  int k   = s*kKs + kk;
  dst[idx] = (k < kH) ? Whh[col*kH + k] : Wih[col*(kIn+kM) + kIn + (k - kH)];
}

// gatesXp[t][b][j][g] = sum_k x_t[b][k]*Wih[g*256+j][k] + bih + bhh
__global__ void k_gatesx(const float* __restrict__ X, const float* __restrict__ Y,
                         const float* __restrict__ WixT_e, const float* __restrict__ WixT_d,
                         const float* __restrict__ bih_e, const float* __restrict__ bhh_e,
                         const float* __restrict__ bih_d, const float* __restrict__ bhh_d,
                         float* __restrict__ gatesXp){
  const int t   = blockIdx.x;
  const int col = blockIdx.y*256 + threadIdx.x;
  __shared__ float xl[kB*kIn];
  const float* xsrc;
  if (t < kTenc)       xsrc = X + (size_t)t*kB*kIn;
  else if (t == kTenc) xsrc = X + (size_t)kTenc*kB*kIn;
  else                 xsrc = Y + (size_t)(t-kTenc-1)*kB*kIn;
  for (int i = threadIdx.x; i < kB*kIn; i += 256) xl[i] = xsrc[i];
  __syncthreads();
  const float* WT   = (t < kTenc) ? WixT_e : WixT_d;
  const float  bias = (t < kTenc) ? (bih_e[col] + bhh_e[col]) : (bih_d[col] + bhh_d[col]);
  float acc[kB];
#pragma unroll
  for (int b = 0; b < kB; ++b) acc[b] = bias;
  for (int k = 0; k < kIn; ++k){
    float wk = WT[k*kG + col];
#pragma unroll
    for (int b = 0; b < kB; ++b) acc[b] += wk * xl[b*kIn + k];
  }
  const int j = col & 255, g = col >> 8;
#pragma unroll
  for (int b = 0; b < kB; ++b)
    gatesXp[(((size_t)t*kB + b)*256 + j)*4 + g] = acc[b];
}

__device__ __forceinline__ float wave_suffix_incl(float x, int lane){
#pragma unroll
  for (int off = 1; off < 64; off <<= 1){
    float t = __shfl_down(x, off);
    if (lane + off < 64) x += t;
  }
  return x;
}

__global__ void __launch_bounds__(512, 1)
k_seq(const float* __restrict__ gatesXp, const float* __restrict__ wblob,
      float* __restrict__ pbuf, unsigned int* flags,
      const float* __restrict__ Wd, const float* __restrict__ bd,
      const float* __restrict__ Wu, const float* __restrict__ bu,
      const float* __restrict__ Wv, const float* __restrict__ bv,
      const float* __restrict__ h0, const float* __restrict__ c0,
      float* __restrict__ Hdec){
  const int bid  = blockIdx.x;
  const int b    = bid / kSp;      // batch element
  const int sp   = bid - b*kSp;    // K-split id 0..3
  const int tid  = threadIdx.x;
  const int lane = tid & 63;
  const int wave = tid >> 6;
  const int j    = tid & 255;
  const int gp   = tid >> 8;       // 0: gates i,f ; 1: gates g,o
  const int col0 = (2*gp)*256 + j;
  const int col1 = col0 + 256;

  __shared__ __align__(16) float z[kK];   // [h(256) | r(32)]
  __shared__ float cst[kH];
  __shared__ float gbuf[2][256];          // g,o gates exchange (intra-block)
  __shared__ float sbuf[kCap];
  __shared__ float coeff[kCap];
  __shared__ float Vbuf[kCap*kVs];

  if (tid < kH){ z[tid] = h0[tid]; cst[tid] = c0[tid]; }
  if (tid >= kH && tid < kK) z[tid] = 0.f;
  for (int i = tid; i < kCap; i += 512) sbuf[i] = 0.f;
  if (tid < kVs) Vbuf[tid] = 0.f;         // row 0 (never written, coeff=0)
  __syncthreads();

  float wreg[kWR];

  for (int seg = 0; seg < 2; ++seg){
    // load my fp32 weight slice into VGPRs (once per segment)
    {
      const float* wb = wblob + ((size_t)(seg*kSp + sp)*kWR)*512 + tid;
#pragma unroll
      for (int i = 0; i < kWR; ++i) wreg[i] = wb[(size_t)i*512];
    }

    for (int tt = 0; tt < 128; ++tt){
      const int t = seg*128 + tt;

      // x-part gates (i,f,g,o) of unit j — all threads
      float4 gx = *(const float4*)(gatesXp + (((size_t)t*kB + b)*256 + j)*4);

      // ---- phase 1: matvec over my K-range, 2 gates, pure VGPR
      float a00=0.f,a01=0.f,a02=0.f,a03=0.f,a10=0.f,a11=0.f,a12=0.f,a13=0.f;
      {
        const float4* z4 = (const float4*)z + sp*(kKs/4);
#pragma unroll
        for (int c = 0; c < kKs/4; ++c){
          float4 zz = z4[c];
          a00 += wreg[4*c+0]*zz.x; a01 += wreg[4*c+1]*zz.y;
          a02 += wreg[4*c+2]*zz.z; a03 += wreg[4*c+3]*zz.w;
          a10 += wreg[kKs+4*c+0]*zz.x; a11 += wreg[kKs+4*c+1]*zz.y;
          a12 += wreg[kKs+4*c+2]*zz.z; a13 += wreg[kKs+4*c+3]*zz.w;
        }
      }
      const float acc0 = (a00+a01)+(a02+a03);
      const float acc1 = (a10+a11)+(a12+a13);

      // ---- publish partials (agent scope); block-level release of a step flag
      const int par = t & 1;
      const unsigned want = (unsigned)(t + 1);
      {
        float* myp = pbuf + (((size_t)par*kSp + sp)*kB + b)*kG;
        __hip_atomic_store(&myp[col0], acc0, __ATOMIC_RELAXED, __HIP_MEMORY_SCOPE_AGENT);
        __hip_atomic_store(&myp[col1], acc1, __ATOMIC_RELAXED, __HIP_MEMORY_SCOPE_AGENT);
      }
      asm volatile("s_waitcnt vmcnt(0)" ::: "memory");   // my stores at coherence point
      __syncthreads();                                   // all threads' stores done
      if (tid == 0)
        __hip_atomic_store(&flags[(par*kSp + sp)*kB + b], want,
                           __ATOMIC_RELEASE, __HIP_MEMORY_SCOPE_AGENT);
      if (tid < kSp - 1){                                // 3 pollers, one per partner
        int s2p = sp + 1 + tid; if (s2p >= kSp) s2p -= kSp;
        unsigned int* fl = &flags[(par*kSp + s2p)*kB + b];
        while (__hip_atomic_load(fl, __ATOMIC_ACQUIRE, __HIP_MEMORY_SCOPE_AGENT) < want)
          __builtin_amdgcn_s_sleep(1);
      }
      __syncthreads();                                   // partners' data visible

      // gather partner partials; sum in uniform order s2=0..3 (bitwise-identical
      // gates in all sibling blocks -> identical h/c/stack, no second exchange)
      float g0 = gp ? gx.z : gx.x;
      float g1 = gp ? gx.w : gx.y;
#pragma unroll
      for (int s2 = 0; s2 < kSp; ++s2){
        if (s2 == sp){ g0 += acc0; g1 += acc1; }
        else {
          const float* pp = pbuf + (((size_t)par*kSp + s2)*kB + b)*kG;
          g0 += __hip_atomic_load(&pp[col0], __ATOMIC_RELAXED, __HIP_MEMORY_SCOPE_AGENT);
          g1 += __hip_atomic_load(&pp[col1], __ATOMIC_RELAXED, __HIP_MEMORY_SCOPE_AGENT);
        }
      }
      if (gp){ gbuf[0][j] = g0; gbuf[1][j] = g1; }
      __syncthreads();                       // A: full gates ready

      // ---- phase 2: LSTM cell (threads 0..255)
      if (tid < kH){
        float ig = sigf(g0);                 // gate i
        float fg = sigf(g1);                 // gate f
        float g2 = tanhf_fast(gbuf[0][j]);   // gate g
        float og = sigf(gbuf[1][j]);         // gate o
        float cn = fg*cst[j] + ig*g2;
        cst[j] = cn;
        float hn = og*tanhf_fast(cn);
        z[j] = hn;
        if (seg && sp == 0)
          Hdec[(((size_t)(t - kTenc))*kB + b)*kH + j] = hn;
      }
      __syncthreads();                       // B: h ready

      // ---- phase 3+4: controller + stack (wave0: d,u + scan; tid>=256: v)
      const int cnt = t + 1;
      if (wave == 0){
        const float* Wdu = (lane < 32) ? Wd : Wu;
        const int kl = lane & 31;
        float p = 0.f;
#pragma unroll
        for (int q2 = 0; q2 < 8; ++q2) p += z[kl + 32*q2] * Wdu[kl + 32*q2];
        p += swz<0x401F>(p); p += swz<0x201F>(p); p += swz<0x101F>(p);
        p += swz<0x081F>(p); p += swz<0x041F>(p);
        float o  = __shfl_xor(p, 32);
        float dd = sigf(((lane < 32) ? p : o) + bd[0]);
        float uu = sigf(((lane < 32) ? o : p) + bu[0]);

        float sm[5], sn[5];
        float csum = 0.f;
#pragma unroll
        for (int qq = 0; qq < 5; ++qq){
          int i = lane*5 + qq;
          float sv = (i < cnt) ? sbuf[i] : 0.f;
          sm[qq] = sv; csum += sv;
        }
        float run = wave_suffix_incl(csum, lane) - csum;
        float csum2 = 0.f;
#pragma unroll
        for (int qq = 4; qq >= 0; --qq){
          int i = lane*5 + qq;
          float sv;
          if (i == cnt)      sv = dd;
          else if (i < cnt)  sv = fmaxf(sm[qq] - fmaxf(uu - run, 0.f), 0.f);
          else               sv = 0.f;
          sn[qq] = sv;
          run  += sm[qq];
          csum2 += sv;
        }
#pragma unroll
        for (int qq = 0; qq < 5; ++qq){
          int i = lane*5 + qq;
          if (i < kCap) sbuf[i] = sn[qq];
        }
        float run2 = wave_suffix_incl(csum2, lane) - csum2;
#pragma unroll
        for (int qq = 4; qq >= 0; --qq){
          int i = lane*5 + qq;
          float cf = fminf(sn[qq], fmaxf(1.f - run2, 0.f));
          if (i < kCap) coeff[i] = cf;
          run2 += sn[qq];
        }
      } else if (tid >= 256){
        const int m = (tid - 256) >> 3, l = tid & 7;
        float p = 0.f;
        for (int k2 = l; k2 < kH; k2 += 8) p += z[k2] * Wv[m*kH + k2];
        p += swz<0x101F>(p); p += swz<0x081F>(p); p += swz<0x041F>(p);
        if (l == 0) Vbuf[cnt*kVs + m] = tanhf_fast(p + bv[m]);
      }
      __syncthreads();                       // D: coeff + Vbuf[cnt] ready

      // ---- phase 5: r[m] = sum_i coeff[i]*Vbuf[i][m]
      if (tid < kH){
        const int m = tid >> 3, l = tid & 7;
        float p = 0.f;
        for (int i = l; i <= cnt; i += 8) p += coeff[i]*Vbuf[i*kVs + m];
        p += swz<0x101F>(p); p += swz<0x081F>(p); p += swz<0x041F>(p);
        if (l == 0) z[kH + m] = p;
      }
      __syncthreads();                       // E: z ready for next step
    }
  }
}

// oc = tanh(h@Wo^T + bo); out = log_softmax(oc@Wlin^T + blin)
__global__ void k_out(const float* __restrict__ Hdec,
                      const float* __restrict__ WoT, const float* __restrict__ bo,
                      const float* __restrict__ WlinT, const float* __restrict__ blin,
                      float* __restrict__ out){
  const int row = blockIdx.x;
  const int tid = threadIdx.x;
  __shared__ float hr[kH], oc[kH], lg[kOut], st[2];
  hr[tid] = Hdec[(size_t)row*kH + tid];
  __syncthreads();
  float a = bo[tid];
  for (int k = 0; k < kH; ++k) a += hr[k]*WoT[k*kH + tid];
  oc[tid] = tanhf(a);
  __syncthreads();
  if (tid < kOut){
    float a2 = blin[tid];
    for (int k = 0; k < kH; ++k) a2 += oc[k]*WlinT[k*kOut + tid];
    lg[tid] = a2;
  }
  __syncthreads();
  if (tid < 64){
    float mx = -3.4e38f;
    for (int i = tid; i < kOut; i += 64) mx = fmaxf(mx, lg[i]);
#pragma unroll
    for (int off = 32; off; off >>= 1) mx = fmaxf(mx, __shfl_down(mx, off));
    mx = __shfl(mx, 0);
    float se = 0.f;
    for (int i = tid; i < kOut; i += 64) se += expf(lg[i] - mx);
#pragma unroll
    for (int off = 32; off; off >>= 1) se += __shfl_down(se, off);
    if (tid == 0){ st[0] = mx; st[1] = logf(se); }
  }
  __syncthreads();
  if (tid < kOut) out[(size_t)row*kOut + tid] = lg[tid] - st[0] - st[1];
}

extern "C" void kernel_launch(void* const* d_in, const int* in_sizes, int n_in,
                              void* d_out, int out_size, void* d_ws, size_t ws_size,
                              hipStream_t stream){
  (void)in_sizes; (void)n_in; (void)out_size; (void)ws_size;
  const float* X     = (const float*)d_in[0];
  const float* Y     = (const float*)d_in[1];
  const float* Wih_e = (const float*)d_in[2];
  const float* Whh_e = (const float*)d_in[3];
  const float* bih_e = (const float*)d_in[4];
  const float* bhh_e = (const float*)d_in[5];
  const float* Wih_d = (const float*)d_in[6];
  const float* Whh_d = (const float*)d_in[7];
  const float* bih_d = (const float*)d_in[8];
  const float* bhh_d = (const float*)d_in[9];
  const float* Wd    = (const float*)d_in[10];
  const float* bd    = (const float*)d_in[11];
  const float* Wu    = (const float*)d_in[12];
  const float* bu    = (const float*)d_in[13];
  const float* Wv    = (const float*)d_in[14];
  const float* bv    = (const float*)d_in[15];
  const float* Wo    = (const float*)d_in[16];
  const float* bo    = (const float*)d_in[17];
  const float* Wlin  = (const float*)d_in[18];
  const float* blin  = (const float*)d_in[19];
  const float* h0    = (const float*)d_in[20];
  const float* c0    = (const float*)d_in[21];
  float* out = (float*)d_out;

  float* ws = (float*)d_ws;
  size_t o = 0;
  float* gatesXp = ws + o; o += (size_t)kT*kB*kG;        // 8,388,608
  float* WixT_e  = ws + o; o += (size_t)kIn*kG;
  float* WixT_d  = ws + o; o += (size_t)kIn*kG;
  float* WoT     = ws + o; o += (size_t)kH*kH;
  float* WlinT   = ws + o; o += (size_t)kH*kOut;
  float* Hdec    = ws + o; o += (size_t)128*kB*kH;       // 1,048,576
  float* wblob   = ws + o; o += (size_t)2*kSp*kWR*512;   // 589,824
  float* pbuf    = ws + o; o += (size_t)2*kSp*kB*kG;     // 262,144
  unsigned int* flags = (unsigned int*)(ws + o); o += 256; // 2*4*32 = 256 uints

  // flags must start at 0 every launch (harness re-poisons ws to 0xAA)
  hipMemsetAsync(flags, 0, 2*kSp*kB*sizeof(unsigned int), stream);

  auto tr = [&](float* dst, const float* src, int R, int C, int stride, int col0){
    int n = R*C;
    k_transpose<<<(n+255)/256, 256, 0, stream>>>(dst, src, R, C, stride, col0);
  };
  tr(WixT_e, Wih_e, kG, kIn, kIn+kM, 0);
  tr(WixT_d, Wih_d, kG, kIn, kIn+kM, 0);
  tr(WoT,   Wo,   kH,  kH, kH, 0);
  tr(WlinT, Wlin, kOut, kH, kH, 0);

  const int npack = kSp*kWR*512;
  k_packw<<<(npack+255)/256, 256, 0, stream>>>(wblob,                 Wih_e, Whh_e);
  k_packw<<<(npack+255)/256, 256, 0, stream>>>(wblob + (size_t)npack, Wih_d, Whh_d);

  k_gatesx<<<dim3(kT,4), 256, 0, stream>>>(X, Y, WixT_e, WixT_d,
                                           bih_e, bhh_e, bih_d, bhh_d, gatesXp);
  k_seq<<<kB*kSp, 512, 0, stream>>>(gatesXp, wblob, pbuf, flags,
                                    Wd, bd, Wu, bu, Wv, bv, h0, c0, Hdec);
  k_out<<<128*kB, 256, 0, stream>>>(Hdec, WoT, bo, WlinT, blin, out);
}

// Round 7
// 2439.124 us; speedup vs baseline: 3.2440x; 1.0060x over previous
//
#include <hip/hip_runtime.h>
#include <math.h>

typedef unsigned long long u64;

namespace {
constexpr int kH    = 256;   // hidden
constexpr int kM    = 32;    // stack value dim
constexpr int kIn   = 131;   // input dim
constexpr int kOut  = 131;   // output dim
constexpr int kB    = 32;    // batch
constexpr int kTenc = 128;   // encoder steps
constexpr int kT    = 256;   // total sequential steps
constexpr int kCap  = 257;   // stack capacity
constexpr int kG    = 1024;  // 4*H gates
constexpr int kK    = 288;   // H + M combined recurrent input
constexpr int kSp   = 4;     // K-splits (cooperating blocks per batch)
constexpr int kKs   = 72;    // K per split
constexpr int kWR   = 144;   // fp32 weights per thread (2 gates x 72 k), VGPR-resident
constexpr int kVs   = 36;    // Vbuf row stride (bank = (4i+m)%32 -> <=2-way)
}

__device__ __forceinline__ float frcp(float x){ return __builtin_amdgcn_rcpf(x); }
__device__ __forceinline__ float sigf(float x){ return frcp(1.0f + __expf(-x)); }
__device__ __forceinline__ float tanhf_fast(float x){
  return 1.0f - 2.0f*frcp(__expf(2.0f*x) + 1.0f);   // saturates via inf/0
}

template<int PAT>
__device__ __forceinline__ float swz(float x){
  return __int_as_float(__builtin_amdgcn_ds_swizzle(__float_as_int(x), PAT));
}

// dst[c*R + r] = src[r*stride + col0 + c]
__global__ void k_transpose(float* __restrict__ dst, const float* __restrict__ src,
                            int R, int C, int stride, int col0){
  int idx = blockIdx.x*256 + threadIdx.x;
  if (idx >= R*C) return;
  int rr = idx / C;
  int cc = idx - rr*C;
  dst[cc*R + rr] = src[rr*stride + col0 + cc];
}

// fp32 weight pack for the K-split resident k_seq.
// dst[(s*kWR + i)*512 + tid], i = gs*kKs + kk:
//   thread tid (j=tid&255, gp=tid>>8) gate col=(2gp+gs)*256+j, k = s*kKs+kk
//   k<256 -> Whh[col][k], else Wih[col][131 + (k-256)]
__global__ void k_packw(float* __restrict__ dst, const float* __restrict__ Wih,
                        const float* __restrict__ Whh){
  int idx = blockIdx.x*256 + threadIdx.x;
  if (idx >= kSp*kWR*512) return;
  int tid  = idx & 511;
  int rest = idx >> 9;             // s*kWR + i
  int s  = rest / kWR, i = rest - s*kWR;
  int gs = i / kKs,   kk = i - gs*kKs;
  int j  = tid & 255, gp = tid >> 8;
  int col = (2*gp + gs)*256 + j;
  int k   = s*kKs + kk;
  dst[idx] = (k < kH) ? Whh[col*kH + k] : Wih[col*(kIn+kM) + kIn + (k - kH)];
}

// gatesXp[t][b][j][g] = sum_k x_t[b][k]*Wih[g*256+j][k] + bih + bhh
__global__ void k_gatesx(const float* __restrict__ X, const float* __restrict__ Y,
                         const float* __restrict__ WixT_e, const float* __restrict__ WixT_d,
                         const float* __restrict__ bih_e, const float* __restrict__ bhh_e,
                         const float* __restrict__ bih_d, const float* __restrict__ bhh_d,
                         float* __restrict__ gatesXp){
  const int t   = blockIdx.x;
  const int col = blockIdx.y*256 + threadIdx.x;
  __shared__ float xl[kB*kIn];
  const float* xsrc;
  if (t < kTenc)       xsrc = X + (size_t)t*kB*kIn;
  else if (t == kTenc) xsrc = X + (size_t)kTenc*kB*kIn;
  else                 xsrc = Y + (size_t)(t-kTenc-1)*kB*kIn;
  for (int i = threadIdx.x; i < kB*kIn; i += 256) xl[i] = xsrc[i];
  __syncthreads();
  const float* WT   = (t < kTenc) ? WixT_e : WixT_d;
  const float  bias = (t < kTenc) ? (bih_e[col] + bhh_e[col]) : (bih_d[col] + bhh_d[col]);
  float acc[kB];
#pragma unroll
  for (int b = 0; b < kB; ++b) acc[b] = bias;
  for (int k = 0; k < kIn; ++k){
    float wk = WT[k*kG + col];
#pragma unroll
    for (int b = 0; b < kB; ++b) acc[b] += wk * xl[b*kIn + k];
  }
  const int j = col & 255, g = col >> 8;
#pragma unroll
  for (int b = 0; b < kB; ++b)
    gatesXp[(((size_t)t*kB + b)*256 + j)*4 + g] = acc[b];
}

__device__ __forceinline__ float wave_suffix_incl(float x, int lane){
#pragma unroll
  for (int off = 1; off < 64; off <<= 1){
    float t = __shfl_down(x, off);
    if (lane + off < 64) x += t;
  }
  return x;
}

__global__ void __launch_bounds__(512, 1)
k_seq(const float* __restrict__ gatesXp, const float* __restrict__ wblob,
      u64* __restrict__ pbuf2, unsigned int* flags,
      const float* __restrict__ Wd, const float* __restrict__ bd,
      const float* __restrict__ Wu, const float* __restrict__ bu,
      const float* __restrict__ Wv, const float* __restrict__ bv,
      const float* __restrict__ h0, const float* __restrict__ c0,
      float* __restrict__ Hdec){
  const int bid  = blockIdx.x;
  const int b    = bid / kSp;      // batch element
  const int sp   = bid - b*kSp;    // K-split id 0..3
  const int tid  = threadIdx.x;
  const int lane = tid & 63;
  const int wave = tid >> 6;
  const int j    = tid & 255;
  const int gp   = tid >> 8;       // 0: gates i,f ; 1: gates g,o

  __shared__ __align__(16) float z[kK];   // [h(256) | r(32)]
  __shared__ float cst[kH];
  __shared__ float gbuf[2][256];          // g,o gates exchange (intra-block)
  __shared__ float sbuf[kCap];
  __shared__ float coeff[kCap];
  __shared__ float Vbuf[kCap*kVs];

  if (tid < kH){ z[tid] = h0[tid]; cst[tid] = c0[tid]; }
  if (tid >= kH && tid < kK) z[tid] = 0.f;
  for (int i = tid; i < kCap; i += 512) sbuf[i] = 0.f;
  if (tid < kVs) Vbuf[tid] = 0.f;         // row 0 (never written, coeff=0)
  __syncthreads();

  float wreg[kWR];

  for (int seg = 0; seg < 2; ++seg){
    // load my fp32 weight slice into VGPRs (once per segment)
    {
      const float* wb = wblob + ((size_t)(seg*kSp + sp)*kWR)*512 + tid;
#pragma unroll
      for (int i = 0; i < kWR; ++i) wreg[i] = wb[(size_t)i*512];
    }
    // force materialization: asm output is not rematerializable, so the
    // compiler cannot sink these loads back into the timestep loop
#pragma unroll
    for (int i = 0; i < kWR; ++i) asm volatile("" : "+v"(wreg[i]));

    for (int tt = 0; tt < 128; ++tt){
      const int t = seg*128 + tt;

      // x-part gates (i,f,g,o) of unit j — all threads
      float4 gx = *(const float4*)(gatesXp + (((size_t)t*kB + b)*256 + j)*4);

      // ---- phase 1: matvec over my K-range, 2 gates, pure VGPR
      float a00=0.f,a01=0.f,a02=0.f,a03=0.f,a10=0.f,a11=0.f,a12=0.f,a13=0.f;
      {
        const float4* z4 = (const float4*)z + sp*(kKs/4);
#pragma unroll
        for (int c = 0; c < kKs/4; ++c){
          float4 zz = z4[c];
          a00 += wreg[4*c+0]*zz.x; a01 += wreg[4*c+1]*zz.y;
          a02 += wreg[4*c+2]*zz.z; a03 += wreg[4*c+3]*zz.w;
          a10 += wreg[kKs+4*c+0]*zz.x; a11 += wreg[kKs+4*c+1]*zz.y;
          a12 += wreg[kKs+4*c+2]*zz.z; a13 += wreg[kKs+4*c+3]*zz.w;
        }
      }
      const float acc0 = (a00+a01)+(a02+a03);
      const float acc1 = (a10+a11)+(a12+a13);

      // ---- publish packed partials (one 8B agent-scope store per thread)
      const int par = t & 1;
      const unsigned want = (unsigned)(t + 1);
      const u64 mine = (__builtin_bit_cast(u64, float2{acc0, acc1}));
      __hip_atomic_store(pbuf2 + (((size_t)par*kSp + sp)*kB + b)*512 + tid, mine,
                         __ATOMIC_RELAXED, __HIP_MEMORY_SCOPE_AGENT);
      asm volatile("s_waitcnt vmcnt(0)" ::: "memory");   // my stores visible
      __syncthreads();                                   // whole block's stores done
      if (tid == 0)
        __hip_atomic_store(&flags[(par*kSp + sp)*kB + b], want,
                           __ATOMIC_RELEASE, __HIP_MEMORY_SCOPE_AGENT);
      if (tid < kSp - 1){                                // 3 pollers, one per partner
        int s2p = sp + 1 + tid; if (s2p >= kSp) s2p -= kSp;
        unsigned int* fl = &flags[(par*kSp + s2p)*kB + b];
        while (__hip_atomic_load(fl, __ATOMIC_ACQUIRE, __HIP_MEMORY_SCOPE_AGENT) < want){}
      }
      __syncthreads();                                   // partners' data visible

      // gather partner partials (issue all loads first), then sum in the
      // uniform order s2=0..3 — bitwise-identical gates in all sibling blocks
      u64 pv[kSp];
#pragma unroll
      for (int s2 = 0; s2 < kSp; ++s2){
        if (s2 != sp)
          pv[s2] = __hip_atomic_load(pbuf2 + (((size_t)par*kSp + s2)*kB + b)*512 + tid,
                                     __ATOMIC_RELAXED, __HIP_MEMORY_SCOPE_AGENT);
      }
#pragma unroll
      for (int s2 = 0; s2 < kSp; ++s2) if (s2 == sp) pv[s2] = mine;

      float g0 = gp ? gx.z : gx.x;
      float g1 = gp ? gx.w : gx.y;
#pragma unroll
      for (int s2 = 0; s2 < kSp; ++s2){
        float2 pp = __builtin_bit_cast(float2, pv[s2]);
        g0 += pp.x; g1 += pp.y;
      }
      if (gp){ gbuf[0][j] = g0; gbuf[1][j] = g1; }
      __syncthreads();                       // A: full gates ready

      // ---- phase 2: LSTM cell (threads 0..255)
      if (tid < kH){
        float ig = sigf(g0);                 // gate i
        float fg = sigf(g1);                 // gate f
        float g2 = tanhf_fast(gbuf[0][j]);   // gate g
        float og = sigf(gbuf[1][j]);         // gate o
        float cn = fg*cst[j] + ig*g2;
        cst[j] = cn;
        float hn = og*tanhf_fast(cn);
        z[j] = hn;
        if (seg && sp == 0)
          Hdec[(((size_t)(t - kTenc))*kB + b)*kH + j] = hn;
      }
      __syncthreads();                       // B: h ready

      // ---- phase 3+4: controller + stack (wave0: d,u + scan; tid>=256: v)
      const int cnt = t + 1;
      if (wave == 0){
        const float* Wdu = (lane < 32) ? Wd : Wu;
        const int kl = lane & 31;
        float p = 0.f;
#pragma unroll
        for (int q2 = 0; q2 < 8; ++q2) p += z[kl + 32*q2] * Wdu[kl + 32*q2];
        p += swz<0x401F>(p); p += swz<0x201F>(p); p += swz<0x101F>(p);
        p += swz<0x081F>(p); p += swz<0x041F>(p);
        float o  = __shfl_xor(p, 32);
        float dd = sigf(((lane < 32) ? p : o) + bd[0]);
        float uu = sigf(((lane < 32) ? o : p) + bu[0]);

        float sm[5], sn[5];
        float csum = 0.f;
#pragma unroll
        for (int qq = 0; qq < 5; ++qq){
          int i = lane*5 + qq;
          float sv = (i < cnt) ? sbuf[i] : 0.f;
          sm[qq] = sv; csum += sv;
        }
        float run = wave_suffix_incl(csum, lane) - csum;
        float csum2 = 0.f;
#pragma unroll
        for (int qq = 4; qq >= 0; --qq){
          int i = lane*5 + qq;
          float sv;
          if (i == cnt)      sv = dd;
          else if (i < cnt)  sv = fmaxf(sm[qq] - fmaxf(uu - run, 0.f), 0.f);
          else               sv = 0.f;
          sn[qq] = sv;
          run  += sm[qq];
          csum2 += sv;
        }
#pragma unroll
        for (int qq = 0; qq < 5; ++qq){
          int i = lane*5 + qq;
          if (i < kCap) sbuf[i] = sn[qq];
        }
        float run2 = wave_suffix_incl(csum2, lane) - csum2;
#pragma unroll
        for (int qq = 4; qq >= 0; --qq){
          int i = lane*5 + qq;
          float cf = fminf(sn[qq], fmaxf(1.f - run2, 0.f));
          if (i < kCap) coeff[i] = cf;
          run2 += sn[qq];
        }
      } else if (tid >= 256){
        const int m = (tid - 256) >> 3, l = tid & 7;
        float p = 0.f;
        for (int k2 = l; k2 < kH; k2 += 8) p += z[k2] * Wv[m*kH + k2];
        p += swz<0x101F>(p); p += swz<0x081F>(p); p += swz<0x041F>(p);
        if (l == 0) Vbuf[cnt*kVs + m] = tanhf_fast(p + bv[m]);
      }
      __syncthreads();                       // D: coeff + Vbuf[cnt] ready

      // ---- phase 5: r[m] = sum_i coeff[i]*Vbuf[i][m]
      if (tid < kH){
        const int m = tid >> 3, l = tid & 7;
        float p = 0.f;
        for (int i = l; i <= cnt; i += 8) p += coeff[i]*Vbuf[i*kVs + m];
        p += swz<0x101F>(p); p += swz<0x081F>(p); p += swz<0x041F>(p);
        if (l == 0) z[kH + m] = p;
      }
      __syncthreads();                       // E: z ready for next step
    }
  }
}

// oc = tanh(h@Wo^T + bo); out = log_softmax(oc@Wlin^T + blin)
__global__ void k_out(const float* __restrict__ Hdec,
                      const float* __restrict__ WoT, const float* __restrict__ bo,
                      const float* __restrict__ WlinT, const float* __restrict__ blin,
                      float* __restrict__ out){
  const int row = blockIdx.x;
  const int tid = threadIdx.x;
  __shared__ float hr[kH], oc[kH], lg[kOut], st[2];
  hr[tid] = Hdec[(size_t)row*kH + tid];
  __syncthreads();
  float a = bo[tid];
  for (int k = 0; k < kH; ++k) a += hr[k]*WoT[k*kH + tid];
  oc[tid] = tanhf(a);
  __syncthreads();
  if (tid < kOut){
    float a2 = blin[tid];
    for (int k = 0; k < kH; ++k) a2 += oc[k]*WlinT[k*kOut + tid];
    lg[tid] = a2;
  }
  __syncthreads();
  if (tid < 64){
    float mx = -3.4e38f;
    for (int i = tid; i < kOut; i += 64) mx = fmaxf(mx, lg[i]);
#pragma unroll
    for (int off = 32; off; off >>= 1) mx = fmaxf(mx, __shfl_down(mx, off));
    mx = __shfl(mx, 0);
    float se = 0.f;
    for (int i = tid; i < kOut; i += 64) se += expf(lg[i] - mx);
#pragma unroll
    for (int off = 32; off; off >>= 1) se += __shfl_down(se, off);
    if (tid == 0){ st[0] = mx; st[1] = logf(se); }
  }
  __syncthreads();
  if (tid < kOut) out[(size_t)row*kOut + tid] = lg[tid] - st[0] - st[1];
}

extern "C" void kernel_launch(void* const* d_in, const int* in_sizes, int n_in,
                              void* d_out, int out_size, void* d_ws, size_t ws_size,
                              hipStream_t stream){
  (void)in_sizes; (void)n_in; (void)out_size; (void)ws_size;
  const float* X     = (const float*)d_in[0];
  const float* Y     = (const float*)d_in[1];
  const float* Wih_e = (const float*)d_in[2];
  const float* Whh_e = (const float*)d_in[3];
  const float* bih_e = (const float*)d_in[4];
  const float* bhh_e = (const float*)d_in[5];
  const float* Wih_d = (const float*)d_in[6];
  const float* Whh_d = (const float*)d_in[7];
  const float* bih_d = (const float*)d_in[8];
  const float* bhh_d = (const float*)d_in[9];
  const float* Wd    = (const float*)d_in[10];
  const float* bd    = (const float*)d_in[11];
  const float* Wu    = (const float*)d_in[12];
  const float* bu    = (const float*)d_in[13];
  const float* Wv    = (const float*)d_in[14];
  const float* bv    = (const float*)d_in[15];
  const float* Wo    = (const float*)d_in[16];
  const float* bo    = (const float*)d_in[17];
  const float* Wlin  = (const float*)d_in[18];
  const float* blin  = (const float*)d_in[19];
  const float* h0    = (const float*)d_in[20];
  const float* c0    = (const float*)d_in[21];
  float* out = (float*)d_out;

  float* ws = (float*)d_ws;
  size_t o = 0;
  float* gatesXp = ws + o; o += (size_t)kT*kB*kG;        // 8,388,608
  float* WixT_e  = ws + o; o += (size_t)kIn*kG;
  float* WixT_d  = ws + o; o += (size_t)kIn*kG;
  float* WoT     = ws + o; o += (size_t)kH*kH;
  float* WlinT   = ws + o; o += (size_t)kH*kOut;
  float* Hdec    = ws + o; o += (size_t)128*kB*kH;       // 1,048,576
  float* wblob   = ws + o; o += (size_t)2*kSp*kWR*512;   // 589,824
  u64*   pbuf2   = (u64*)(ws + o); o += (size_t)2*2*kSp*kB*512;  // 1 MB (u64 units)
  unsigned int* flags = (unsigned int*)(ws + o); o += 256; // 2*4*32 = 256 uints

  // flags must start at 0 every launch (harness re-poisons ws to 0xAA)
  hipMemsetAsync(flags, 0, 2*kSp*kB*sizeof(unsigned int), stream);

  auto tr = [&](float* dst, const float* src, int R, int C, int stride, int col0){
    int n = R*C;
    k_transpose<<<(n+255)/256, 256, 0, stream>>>(dst, src, R, C, stride, col0);
  };
  tr(WixT_e, Wih_e, kG, kIn, kIn+kM, 0);
  tr(WixT_d, Wih_d, kG, kIn, kIn+kM, 0);
  tr(WoT,   Wo,   kH,  kH, kH, 0);
  tr(WlinT, Wlin, kOut, kH, kH, 0);

  const int npack = kSp*kWR*512;
  k_packw<<<(npack+255)/256, 256, 0, stream>>>(wblob,                 Wih_e, Whh_e);
  k_packw<<<(npack+255)/256, 256, 0, stream>>>(wblob + (size_t)npack, Wih_d, Whh_d);

  k_gatesx<<<dim3(kT,4), 256, 0, stream>>>(X, Y, WixT_e, WixT_d,
                                           bih_e, bhh_e, bih_d, bhh_d, gatesXp);
  k_seq<<<kB*kSp, 512, 0, stream>>>(gatesXp, wblob, pbuf2, flags,
                                    Wd, bd, Wu, bu, Wv, bv, h0, c0, Hdec);
  k_out<<<128*kB, 256, 0, stream>>>(Hdec, WoT, bo, WlinT, blin, out);
}